// Round 1
// baseline (1507.826 us; speedup 1.0000x reference)
//
#include <hip/hip_runtime.h>

#define N_NODES 50000
#define N_EDGES 800000
#define D_IN 128
#define D_OUT 128
#define N_TYPES 4
#define LN_EPS 1e-5f
#define TE 128        // edges per block in edge kernel
#define KC 16         // fp32 k-chunk for self kernel

typedef __attribute__((ext_vector_type(4))) float f32x4;
typedef __attribute__((ext_vector_type(8))) __bf16 bf16x8;
typedef __attribute__((ext_vector_type(8))) unsigned short u16x8;

// ---- workspace layout (bytes) ----
#define WS_SORTED 64
#define WS_XB     (WS_SORTED + N_EDGES * 4)            // 3,200,064
#define WS_W1T    (WS_XB + N_NODES * D_IN * 2)         // 16,000,064
#define WS_W2T    (WS_W1T + N_TYPES * 8 * 128 * 32 * 2)
#define WS_TOTAL  (WS_W2T + N_TYPES * 4 * 128 * 32 * 2)

__device__ __forceinline__ unsigned short f2bf(float f) {
    unsigned int u = __builtin_bit_cast(unsigned int, f);
    u += 0x7FFFu + ((u >> 16) & 1u);   // RNE; inputs finite
    return (unsigned short)(u >> 16);
}

// ---------------- prep kernels ----------------
__global__ void k_cvt_x(const float* __restrict__ x, unsigned short* __restrict__ xb) {
    int i = blockIdx.x * blockDim.x + threadIdx.x;
    if (i * 4 >= N_NODES * D_IN) return;
    const float4 v = reinterpret_cast<const float4*>(x)[i];
    ushort4 o;
    o.x = f2bf(v.x); o.y = f2bf(v.y); o.z = f2bf(v.z); o.w = f2bf(v.w);
    reinterpret_cast<ushort4*>(xb)[i] = o;
}

// w1Ts[t][ks][f][kk] = w1[t][ks*32+kk][f]   (bf16, k-chunked transposed)
__global__ void k_prep_w1(const float* __restrict__ w1, unsigned short* __restrict__ w1Ts) {
    int gid = blockIdx.x * blockDim.x + threadIdx.x;
    if (gid >= N_TYPES * 8 * 128 * 32) return;
    int kk = gid & 31;
    int f  = (gid >> 5) & 127;
    int ks = (gid >> 12) & 7;
    int t  = gid >> 15;
    float v = w1[((size_t)t * 256 + ks * 32 + kk) * 128 + f];
    w1Ts[gid] = f2bf(v);
}

__global__ void k_prep_w2(const float* __restrict__ w2, unsigned short* __restrict__ w2Ts) {
    int gid = blockIdx.x * blockDim.x + threadIdx.x;
    if (gid >= N_TYPES * 4 * 128 * 32) return;
    int kk = gid & 31;
    int f  = (gid >> 5) & 127;
    int ks = (gid >> 12) & 3;
    int t  = gid >> 14;
    float v = w2[((size_t)t * 128 + ks * 32 + kk) * 128 + f];
    w2Ts[gid] = f2bf(v);
}

// ---------------- type counting sort ----------------
__global__ void k_hist(const int* __restrict__ attr, int* __restrict__ meta) {
    __shared__ int lc[N_TYPES];
    int tid = threadIdx.x;
    if (tid < N_TYPES) lc[tid] = 0;
    __syncthreads();
    int e = blockIdx.x * blockDim.x + tid;
    if (e < N_EDGES) atomicAdd(&lc[attr[e]], 1);
    __syncthreads();
    if (tid < N_TYPES) atomicAdd(&meta[tid], lc[tid]);
}

__global__ void k_scan(int* meta) {
    int off = 0;
    for (int t = 0; t < N_TYPES; ++t) {
        meta[4 + t] = off;   // offsets
        meta[8 + t] = off;   // cursors
        off += meta[t];
    }
}

__global__ void k_scatter(const int* __restrict__ attr, int* __restrict__ meta,
                          int* __restrict__ sorted) {
    __shared__ int lc[N_TYPES];
    __shared__ int base[N_TYPES];
    int tid = threadIdx.x;
    if (tid < N_TYPES) lc[tid] = 0;
    __syncthreads();
    int e = blockIdx.x * blockDim.x + tid;
    int t = -1, rank = 0;
    if (e < N_EDGES) {
        t = attr[e];
        rank = atomicAdd(&lc[t], 1);
    }
    __syncthreads();
    if (tid < N_TYPES) base[tid] = atomicAdd(&meta[8 + tid], lc[tid]);
    __syncthreads();
    if (t >= 0) sorted[base[t] + rank] = e;
}

// ---------------- edge MLP (bf16 MFMA) ----------------
// per block: 128 edges of one type. layer1: D[f][e] = W1^T(128x256) * ef^T(256x128)
// layer2: D[f][e] = W2^T(128x128) * h^T(128x128). atomicAdd into out by col.
__global__ __launch_bounds__(256, 2) void k_edge(
    const unsigned short* __restrict__ xb,
    const int* __restrict__ ei,
    const int* __restrict__ meta,
    const int* __restrict__ sorted,
    const unsigned short* __restrict__ w1Ts,
    const float* __restrict__ b1,
    const unsigned short* __restrict__ w2Ts,
    const float* __restrict__ b2,
    float* __restrict__ out)
{
    const int t = blockIdx.y;
    const int cnt = meta[t];
    const int start = blockIdx.x * TE;
    if (start >= cnt) return;
    const int nval = min(TE, cnt - start);
    const int base = meta[4 + t] + start;

    __shared__ __align__(16) unsigned short sEF[TE * 264];  // ef[e][k0..255], stride 264; aliased as hE[e][fin] stride 136
    __shared__ __align__(16) unsigned short sW[128 * 32];   // weight chunk [f][kk]
    __shared__ int sRowS[TE];
    __shared__ int sColS[TE];

    const int tid = threadIdx.x;
    const int lane = tid & 63;
    const int w = tid >> 6;
    const int g = lane >> 4;   // 0..3
    const int c = lane & 15;   // 0..15
    const int wf = w >> 1;     // f-tile half
    const int we = w & 1;      // e-tile half

    if (tid < TE) {
        int e = sorted[base + min(tid, nval - 1)];
        sRowS[tid] = ei[e];
        sColS[tid] = ei[N_EDGES + e];
    }
    __syncthreads();

    // gather: ef[e][0..127] = xb[row], ef[e][128..255] = xb[col]
    {
        const int hf = g & 1;
        const int ep = g >> 1;
        #pragma unroll
        for (int it = 0; it < 16; ++it) {
            int eL = w * 32 + it * 2 + ep;
            if (eL < nval) {
                int src = hf ? sColS[eL] : sRowS[eL];
                const u16x8 v = *reinterpret_cast<const u16x8*>(xb + (size_t)src * D_IN + c * 8);
                *reinterpret_cast<u16x8*>(&sEF[eL * 264 + hf * 128 + c * 8]) = v;
            }
        }
    }

    float b1v[4][4];
    #pragma unroll
    for (int ft = 0; ft < 4; ++ft)
        #pragma unroll
        for (int r = 0; r < 4; ++r)
            b1v[ft][r] = b1[t * D_OUT + 64 * wf + 16 * ft + 4 * g + r];

    f32x4 acc[4][4];
    #pragma unroll
    for (int ft = 0; ft < 4; ++ft)
        #pragma unroll
        for (int et = 0; et < 4; ++et)
            acc[ft][et] = f32x4{0.f, 0.f, 0.f, 0.f};

    __syncthreads();   // gather complete

    // ---- layer 1: K = 256, 8 k-steps ----
    for (int ks = 0; ks < 8; ++ks) {
        {
            const u16x8* gsrc = reinterpret_cast<const u16x8*>(w1Ts + (size_t)(t * 8 + ks) * 4096);
            u16x8* ldst = reinterpret_cast<u16x8*>(sW);
            ldst[tid] = gsrc[tid];
            ldst[tid + 256] = gsrc[tid + 256];
        }
        __syncthreads();
        bf16x8 af[4], bfr[4];
        #pragma unroll
        for (int ft = 0; ft < 4; ++ft)
            af[ft] = *reinterpret_cast<const bf16x8*>(&sW[(64 * wf + 16 * ft + c) * 32 + 8 * g]);
        #pragma unroll
        for (int et = 0; et < 4; ++et)
            bfr[et] = *reinterpret_cast<const bf16x8*>(&sEF[(64 * we + 16 * et + c) * 264 + ks * 32 + 8 * g]);
        #pragma unroll
        for (int ft = 0; ft < 4; ++ft)
            #pragma unroll
            for (int et = 0; et < 4; ++et)
                acc[ft][et] = __builtin_amdgcn_mfma_f32_16x16x32_bf16(af[ft], bfr[et], acc[ft][et], 0, 0, 0);
        __syncthreads();
    }

    // h = relu(acc + b1) -> hE[e][fin] (stride 136 shorts), aliases sEF
    {
        unsigned int* hE = reinterpret_cast<unsigned int*>(sEF);
        #pragma unroll
        for (int ft = 0; ft < 4; ++ft) {
            #pragma unroll
            for (int et = 0; et < 4; ++et) {
                int e = 64 * we + 16 * et + c;
                int fb = 32 * wf + 8 * ft + 2 * g;   // u32 index within row
                float h0 = fmaxf(acc[ft][et][0] + b1v[ft][0], 0.f);
                float h1 = fmaxf(acc[ft][et][1] + b1v[ft][1], 0.f);
                float h2 = fmaxf(acc[ft][et][2] + b1v[ft][2], 0.f);
                float h3 = fmaxf(acc[ft][et][3] + b1v[ft][3], 0.f);
                hE[e * 68 + fb + 0] = (unsigned int)f2bf(h0) | ((unsigned int)f2bf(h1) << 16);
                hE[e * 68 + fb + 1] = (unsigned int)f2bf(h2) | ((unsigned int)f2bf(h3) << 16);
            }
        }
    }

    f32x4 acc2[4][4];
    #pragma unroll
    for (int ft = 0; ft < 4; ++ft)
        #pragma unroll
        for (int et = 0; et < 4; ++et)
            acc2[ft][et] = f32x4{0.f, 0.f, 0.f, 0.f};

    // ---- layer 2: K = 128, 4 k-steps ----
    for (int ks = 0; ks < 4; ++ks) {
        {
            const u16x8* gsrc = reinterpret_cast<const u16x8*>(w2Ts + (size_t)(t * 4 + ks) * 4096);
            u16x8* ldst = reinterpret_cast<u16x8*>(sW);
            ldst[tid] = gsrc[tid];
            ldst[tid + 256] = gsrc[tid + 256];
        }
        __syncthreads();
        bf16x8 af[4], bfr[4];
        #pragma unroll
        for (int ft = 0; ft < 4; ++ft)
            af[ft] = *reinterpret_cast<const bf16x8*>(&sW[(64 * wf + 16 * ft + c) * 32 + 8 * g]);
        #pragma unroll
        for (int et = 0; et < 4; ++et)
            bfr[et] = *reinterpret_cast<const bf16x8*>(&sEF[(64 * we + 16 * et + c) * 136 + ks * 32 + 8 * g]);
        #pragma unroll
        for (int ft = 0; ft < 4; ++ft)
            #pragma unroll
            for (int et = 0; et < 4; ++et)
                acc2[ft][et] = __builtin_amdgcn_mfma_f32_16x16x32_bf16(af[ft], bfr[et], acc2[ft][et], 0, 0, 0);
        __syncthreads();
    }

    // scatter: out[col[e]][fout] += m
    float b2v[4][4];
    #pragma unroll
    for (int ft = 0; ft < 4; ++ft)
        #pragma unroll
        for (int r = 0; r < 4; ++r)
            b2v[ft][r] = b2[t * D_OUT + 64 * wf + 16 * ft + 4 * g + r];

    #pragma unroll
    for (int et = 0; et < 4; ++et) {
        int e = 64 * we + 16 * et + c;
        if (e < nval) {
            float* orow = out + (size_t)sColS[e] * D_OUT;
            #pragma unroll
            for (int ft = 0; ft < 4; ++ft) {
                int fb = 64 * wf + 16 * ft + 4 * g;
                #pragma unroll
                for (int r = 0; r < 4; ++r)
                    atomicAdd(&orow[fb + r], acc2[ft][et][r] + b2v[ft][r]);
            }
        }
    }
}

// ---------------- self-loop GEMM + accum + ReLU + LayerNorm (fp32) ----------------
__global__ __launch_bounds__(256, 2) void k_self_ln(
    const float* __restrict__ x,
    const float* __restrict__ sw,
    const float* __restrict__ sb,
    const float* __restrict__ gamma,
    const float* __restrict__ beta,
    float* __restrict__ out)
{
    const int nb = blockIdx.x * 64;
    const int nClamp = min(64, N_NODES - nb);
    __shared__ __align__(16) float smA[64 * 129];   // x rows; later relu'd pre-LN rows
    __shared__ __align__(16) float smW[KC * 128];
    __shared__ float sRed[256], sRed2[256];
    __shared__ float sMu[64], sRstd[64];
    const int tid = threadIdx.x;

    // stage x rows (coalesced)
    for (int r = 0; r < 8; ++r) {
        int f4 = tid + 256 * r;
        int node = f4 >> 5;
        int k = (f4 & 31) * 4;
        if (node < nClamp) {
            const float4 v = *reinterpret_cast<const float4*>(x + (size_t)(nb + node) * D_IN + k);
            float* dst = &smA[node * 129 + k];
            dst[0] = v.x; dst[1] = v.y; dst[2] = v.z; dst[3] = v.w;
        }
    }

    const int eg = tid & 15, fg = tid >> 4, f0 = fg * 8;
    float acc[4][8];
    #pragma unroll
    for (int i = 0; i < 8; ++i) {
        float bv = sb[f0 + i];
        #pragma unroll
        for (int j = 0; j < 4; ++j) acc[j][i] = bv;
    }

    for (int kc = 0; kc < D_IN / KC; ++kc) {
        __syncthreads();   // covers gather (kc=0) and prev compute
        {
            const float4* gsrc = reinterpret_cast<const float4*>(sw + kc * KC * 128);
            float4* ldst = reinterpret_cast<float4*>(smW);
            ldst[tid] = gsrc[tid];
            ldst[tid + 256] = gsrc[tid + 256];
        }
        __syncthreads();
        #pragma unroll
        for (int kk = 0; kk < KC; ++kk) {
            float a[4];
            #pragma unroll
            for (int j = 0; j < 4; ++j) a[j] = smA[(eg * 4 + j) * 129 + kc * KC + kk];
            const float4 w0 = *reinterpret_cast<const float4*>(&smW[kk * 128 + f0]);
            const float4 w1v = *reinterpret_cast<const float4*>(&smW[kk * 128 + f0 + 4]);
            float wv[8] = {w0.x, w0.y, w0.z, w0.w, w1v.x, w1v.y, w1v.z, w1v.w};
            #pragma unroll
            for (int j = 0; j < 4; ++j)
                #pragma unroll
                for (int i = 0; i < 8; ++i)
                    acc[j][i] = fmaf(a[j], wv[i], acc[j][i]);
        }
    }
    __syncthreads();

    // add aggregated messages, relu, store pre-LN rows back to smA (alias)
    #pragma unroll
    for (int j = 0; j < 4; ++j) {
        int node = eg * 4 + j;
        if (node < nClamp) {
            const float* arow = out + (size_t)(nb + node) * D_OUT + f0;
            #pragma unroll
            for (int i = 0; i < 8; ++i) {
                float v = acc[j][i] + arow[i];
                smA[node * 129 + f0 + i] = fmaxf(v, 0.f);
            }
        }
    }
    __syncthreads();

    // LayerNorm reduce
    {
        int node = tid >> 2, q = tid & 3;
        float s = 0.f, ss = 0.f;
        #pragma unroll
        for (int i = 0; i < 32; ++i) {
            float v = smA[node * 129 + q * 32 + i];
            s += v; ss += v * v;
        }
        sRed[tid] = s; sRed2[tid] = ss;
    }
    __syncthreads();
    if (tid < 64) {
        float s = sRed[tid * 4] + sRed[tid * 4 + 1] + sRed[tid * 4 + 2] + sRed[tid * 4 + 3];
        float ss = sRed2[tid * 4] + sRed2[tid * 4 + 1] + sRed2[tid * 4 + 2] + sRed2[tid * 4 + 3];
        float mu = s * (1.f / 128.f);
        float var = ss * (1.f / 128.f) - mu * mu;
        sMu[tid] = mu;
        sRstd[tid] = rsqrtf(var + LN_EPS);
    }
    __syncthreads();

    // normalize + store (coalesced float4)
    for (int r = 0; r < 8; ++r) {
        int f4 = tid + 256 * r;
        int node = f4 >> 5;
        int k = (f4 & 31) * 4;
        if (node < nClamp) {
            float mu = sMu[node], rs = sRstd[node];
            const float4 gm = *reinterpret_cast<const float4*>(gamma + k);
            const float4 bt = *reinterpret_cast<const float4*>(beta + k);
            float4 o;
            o.x = (smA[node * 129 + k + 0] - mu) * rs * gm.x + bt.x;
            o.y = (smA[node * 129 + k + 1] - mu) * rs * gm.y + bt.y;
            o.z = (smA[node * 129 + k + 2] - mu) * rs * gm.z + bt.z;
            o.w = (smA[node * 129 + k + 3] - mu) * rs * gm.w + bt.w;
            *reinterpret_cast<float4*>(out + (size_t)(nb + node) * D_OUT + k) = o;
        }
    }
}

extern "C" void kernel_launch(void* const* d_in, const int* in_sizes, int n_in,
                              void* d_out, int out_size, void* d_ws, size_t ws_size,
                              hipStream_t stream) {
    const float* x     = (const float*)d_in[0];
    const int*   ei    = (const int*)d_in[1];
    const int*   attr  = (const int*)d_in[2];
    const float* w1    = (const float*)d_in[3];
    const float* b1    = (const float*)d_in[4];
    const float* w2    = (const float*)d_in[5];
    const float* b2    = (const float*)d_in[6];
    const float* sw    = (const float*)d_in[7];
    const float* sb    = (const float*)d_in[8];
    const float* gamma = (const float*)d_in[9];
    const float* beta  = (const float*)d_in[10];
    float* out = (float*)d_out;

    if (ws_size < (size_t)WS_TOTAL) return;   // fail visibly rather than corrupt

    char* ws = (char*)d_ws;
    int* meta = (int*)ws;                                   // counts[4], offsets[4], cursors[4]
    int* sorted = (int*)(ws + WS_SORTED);
    unsigned short* xb   = (unsigned short*)(ws + WS_XB);
    unsigned short* w1Ts = (unsigned short*)(ws + WS_W1T);
    unsigned short* w2Ts = (unsigned short*)(ws + WS_W2T);

    hipMemsetAsync(meta, 0, 64, stream);
    hipMemsetAsync(out, 0, (size_t)N_NODES * D_OUT * sizeof(float), stream);

    k_cvt_x<<<(N_NODES * D_IN / 4 + 255) / 256, 256, 0, stream>>>(x, xb);
    k_prep_w1<<<(N_TYPES * 8 * 128 * 32 + 255) / 256, 256, 0, stream>>>(w1, w1Ts);
    k_prep_w2<<<(N_TYPES * 4 * 128 * 32 + 255) / 256, 256, 0, stream>>>(w2, w2Ts);
    k_hist<<<(N_EDGES + 255) / 256, 256, 0, stream>>>(attr, meta);
    k_scan<<<1, 1, 0, stream>>>(meta);
    k_scatter<<<(N_EDGES + 255) / 256, 256, 0, stream>>>(attr, meta, sorted);
    k_edge<<<dim3((N_EDGES + TE - 1) / TE, N_TYPES), 256, 0, stream>>>(
        xb, ei, meta, sorted, w1Ts, b1, w2Ts, b2, out);
    k_self_ln<<<(N_NODES + 63) / 64, 256, 0, stream>>>(x, sw, sb, gamma, beta, out);
}

// Round 2
// 636.643 us; speedup vs baseline: 2.3684x; 2.3684x over previous
//
#include <hip/hip_runtime.h>

#define N_NODES 50000
#define N_EDGES 800000
#define D_IN 128
#define D_OUT 128
#define N_TYPES 4
#define LN_EPS 1e-5f
#define TE 128        // edges per block in edge kernel
#define KC 16         // fp32 k-chunk for self kernel
#define SCAN_T 1024

typedef __attribute__((ext_vector_type(4))) float f32x4;
typedef __attribute__((ext_vector_type(8))) __bf16 bf16x8;
typedef __attribute__((ext_vector_type(8))) unsigned short u16x8;

// ---- workspace layout (bytes), 256-aligned sections ----
constexpr size_t wsal(size_t x) { return (x + 255) & ~size_t(255); }
constexpr size_t OFF_META   = 0;                                            // 64 B
constexpr size_t OFF_SORTED = 256;
constexpr size_t OFF_XB     = OFF_SORTED + wsal((size_t)N_EDGES * 4);
constexpr size_t OFF_W1T    = OFF_XB + wsal((size_t)N_NODES * D_IN * 2);
constexpr size_t OFF_W2T    = OFF_W1T + wsal((size_t)N_TYPES * 8 * 128 * 32 * 2);
constexpr size_t OFF_COLCNT = OFF_W2T + wsal((size_t)N_TYPES * 4 * 128 * 32 * 2);
constexpr size_t OFF_ROWPTR = OFF_COLCNT + wsal((size_t)N_NODES * 4);
constexpr size_t OFF_CURSOR = OFF_ROWPTR + wsal((size_t)(N_NODES + 1) * 4);
constexpr size_t OFF_LIST2  = OFF_CURSOR + wsal((size_t)N_NODES * 4);
constexpr size_t OFF_MSG    = OFF_LIST2 + wsal((size_t)N_EDGES * 4);
constexpr size_t WS_TOTAL_MSG = OFF_MSG + wsal((size_t)N_EDGES * D_OUT * 2);   // ~224.9 MB
constexpr size_t WS_TOTAL_MIN = OFF_COLCNT;                                    // fallback needs

__device__ __forceinline__ unsigned short f2bf(float f) {
    unsigned int u = __builtin_bit_cast(unsigned int, f);
    u += 0x7FFFu + ((u >> 16) & 1u);   // RNE; inputs finite
    return (unsigned short)(u >> 16);
}

// ---------------- prep kernels ----------------
__global__ void k_cvt_x(const float* __restrict__ x, unsigned short* __restrict__ xb) {
    int i = blockIdx.x * blockDim.x + threadIdx.x;
    if (i * 4 >= N_NODES * D_IN) return;
    const float4 v = reinterpret_cast<const float4*>(x)[i];
    ushort4 o;
    o.x = f2bf(v.x); o.y = f2bf(v.y); o.z = f2bf(v.z); o.w = f2bf(v.w);
    reinterpret_cast<ushort4*>(xb)[i] = o;
}

// w1Ts[t][ks][f][kk] = w1[t][ks*32+kk][f]   (bf16, k-chunked transposed)
__global__ void k_prep_w1(const float* __restrict__ w1, unsigned short* __restrict__ w1Ts) {
    int gid = blockIdx.x * blockDim.x + threadIdx.x;
    if (gid >= N_TYPES * 8 * 128 * 32) return;
    int kk = gid & 31;
    int f  = (gid >> 5) & 127;
    int ks = (gid >> 12) & 7;
    int t  = gid >> 15;
    float v = w1[((size_t)t * 256 + ks * 32 + kk) * 128 + f];
    w1Ts[gid] = f2bf(v);
}

__global__ void k_prep_w2(const float* __restrict__ w2, unsigned short* __restrict__ w2Ts) {
    int gid = blockIdx.x * blockDim.x + threadIdx.x;
    if (gid >= N_TYPES * 4 * 128 * 32) return;
    int kk = gid & 31;
    int f  = (gid >> 5) & 127;
    int ks = (gid >> 12) & 3;
    int t  = gid >> 14;
    float v = w2[((size_t)t * 128 + ks * 32 + kk) * 128 + f];
    w2Ts[gid] = f2bf(v);
}

// ---------------- type counting sort ----------------
__global__ void k_hist(const int* __restrict__ attr, int* __restrict__ meta) {
    __shared__ int lc[N_TYPES];
    int tid = threadIdx.x;
    if (tid < N_TYPES) lc[tid] = 0;
    __syncthreads();
    int e = blockIdx.x * blockDim.x + tid;
    if (e < N_EDGES) atomicAdd(&lc[attr[e]], 1);
    __syncthreads();
    if (tid < N_TYPES) atomicAdd(&meta[tid], lc[tid]);
}

__global__ void k_scan(int* meta) {
    int off = 0;
    for (int t = 0; t < N_TYPES; ++t) {
        meta[4 + t] = off;   // offsets
        meta[8 + t] = off;   // cursors
        off += meta[t];
    }
}

__global__ void k_scatter(const int* __restrict__ attr, int* __restrict__ meta,
                          int* __restrict__ sorted) {
    __shared__ int lc[N_TYPES];
    __shared__ int base[N_TYPES];
    int tid = threadIdx.x;
    if (tid < N_TYPES) lc[tid] = 0;
    __syncthreads();
    int e = blockIdx.x * blockDim.x + tid;
    int t = -1, rank = 0;
    if (e < N_EDGES) {
        t = attr[e];
        rank = atomicAdd(&lc[t], 1);
    }
    __syncthreads();
    if (tid < N_TYPES) base[tid] = atomicAdd(&meta[8 + tid], lc[tid]);
    __syncthreads();
    if (t >= 0) sorted[base[t] + rank] = e;
}

// ---------------- CSR by destination (col) ----------------
__global__ void k_hist_col(const int* __restrict__ ei, int* __restrict__ cnt) {
    int e = blockIdx.x * blockDim.x + threadIdx.x;
    if (e < N_EDGES) atomicAdd(&cnt[ei[N_EDGES + e]], 1);
}

__global__ __launch_bounds__(SCAN_T) void k_scan_col(const int* __restrict__ cnt,
                                                     int* __restrict__ rowptr,
                                                     int* __restrict__ cursor) {
    __shared__ int part[SCAN_T];
    const int tid = threadIdx.x;
    const int CH = (N_NODES + SCAN_T - 1) / SCAN_T;
    const int s0 = tid * CH, s1 = min(s0 + CH, N_NODES);
    int sum = 0;
    for (int i = s0; i < s1; ++i) sum += cnt[i];
    part[tid] = sum;
    __syncthreads();
    for (int d = 1; d < SCAN_T; d <<= 1) {
        int v = (tid >= d) ? part[tid - d] : 0;
        __syncthreads();
        part[tid] += v;
        __syncthreads();
    }
    int run = (tid > 0) ? part[tid - 1] : 0;
    for (int i = s0; i < s1; ++i) {
        rowptr[i] = run; cursor[i] = run;
        run += cnt[i];
    }
    if (tid == SCAN_T - 1) rowptr[N_NODES] = run;
}

// list2[csr_pos] = type-sorted position of the edge (msg rows are stored by that position)
__global__ void k_scatter_col(const int* __restrict__ ei, const int* __restrict__ sorted,
                              int* __restrict__ cursor, int* __restrict__ list2) {
    int i = blockIdx.x * blockDim.x + threadIdx.x;
    if (i >= N_EDGES) return;
    int e = sorted[i];
    int c = ei[N_EDGES + e];
    int pos = atomicAdd(&cursor[c], 1);
    list2[pos] = i;
}

// ---------------- edge MLP (bf16 MFMA) ----------------
template <bool USE_MSG>
__global__ __launch_bounds__(256, 2) void k_edge(
    const unsigned short* __restrict__ xb,
    const int* __restrict__ ei,
    const int* __restrict__ meta,
    const int* __restrict__ sorted,
    const unsigned short* __restrict__ w1Ts,
    const float* __restrict__ b1,
    const unsigned short* __restrict__ w2Ts,
    const float* __restrict__ b2,
    float* __restrict__ out,
    unsigned short* __restrict__ msg)
{
    const int t = blockIdx.y;
    const int cnt = meta[t];
    const int start = blockIdx.x * TE;
    if (start >= cnt) return;
    const int nval = min(TE, cnt - start);
    const int base = meta[4 + t] + start;

    __shared__ __align__(16) unsigned short sEF[TE * 264];  // ef[e][k], stride 264; aliased as hE stride 136
    __shared__ __align__(16) unsigned short sW[128 * 32];   // weight chunk [f][kk]
    __shared__ int sRowS[TE];
    __shared__ int sColS[TE];

    const int tid = threadIdx.x;
    const int lane = tid & 63;
    const int w = tid >> 6;
    const int g = lane >> 4;   // 0..3
    const int c = lane & 15;   // 0..15
    const int wf = w >> 1;     // f-tile half
    const int we = w & 1;      // e-tile half

    if (tid < TE) {
        int e = sorted[base + min(tid, nval - 1)];
        sRowS[tid] = ei[e];
        sColS[tid] = ei[N_EDGES + e];
    }
    __syncthreads();

    // gather: ef[e][0..127] = xb[row], ef[e][128..255] = xb[col]
    {
        const int hf = g & 1;
        const int ep = g >> 1;
        #pragma unroll
        for (int it = 0; it < 16; ++it) {
            int eL = w * 32 + it * 2 + ep;
            if (eL < nval) {
                int src = hf ? sColS[eL] : sRowS[eL];
                const u16x8 v = *reinterpret_cast<const u16x8*>(xb + (size_t)src * D_IN + c * 8);
                *reinterpret_cast<u16x8*>(&sEF[eL * 264 + hf * 128 + c * 8]) = v;
            }
        }
    }

    float b1v[4][4];
    #pragma unroll
    for (int ft = 0; ft < 4; ++ft)
        #pragma unroll
        for (int r = 0; r < 4; ++r)
            b1v[ft][r] = b1[t * D_OUT + 64 * wf + 16 * ft + 4 * g + r];

    f32x4 acc[4][4];
    #pragma unroll
    for (int ft = 0; ft < 4; ++ft)
        #pragma unroll
        for (int et = 0; et < 4; ++et)
            acc[ft][et] = f32x4{0.f, 0.f, 0.f, 0.f};

    __syncthreads();   // gather complete

    // ---- layer 1: K = 256, 8 k-steps ----
    for (int ks = 0; ks < 8; ++ks) {
        {
            const u16x8* gsrc = reinterpret_cast<const u16x8*>(w1Ts + (size_t)(t * 8 + ks) * 4096);
            u16x8* ldst = reinterpret_cast<u16x8*>(sW);
            ldst[tid] = gsrc[tid];
            ldst[tid + 256] = gsrc[tid + 256];
        }
        __syncthreads();
        bf16x8 af[4], bfr[4];
        #pragma unroll
        for (int ft = 0; ft < 4; ++ft)
            af[ft] = *reinterpret_cast<const bf16x8*>(&sW[(64 * wf + 16 * ft + c) * 32 + 8 * g]);
        #pragma unroll
        for (int et = 0; et < 4; ++et)
            bfr[et] = *reinterpret_cast<const bf16x8*>(&sEF[(64 * we + 16 * et + c) * 264 + ks * 32 + 8 * g]);
        #pragma unroll
        for (int ft = 0; ft < 4; ++ft)
            #pragma unroll
            for (int et = 0; et < 4; ++et)
                acc[ft][et] = __builtin_amdgcn_mfma_f32_16x16x32_bf16(af[ft], bfr[et], acc[ft][et], 0, 0, 0);
        __syncthreads();
    }

    // h = relu(acc + b1) -> hE[e][fin] (stride 136 shorts), aliases sEF
    {
        unsigned int* hE = reinterpret_cast<unsigned int*>(sEF);
        #pragma unroll
        for (int ft = 0; ft < 4; ++ft) {
            #pragma unroll
            for (int et = 0; et < 4; ++et) {
                int e = 64 * we + 16 * et + c;
                int fb = 32 * wf + 8 * ft + 2 * g;   // u32 index within row
                float h0 = fmaxf(acc[ft][et][0] + b1v[ft][0], 0.f);
                float h1 = fmaxf(acc[ft][et][1] + b1v[ft][1], 0.f);
                float h2 = fmaxf(acc[ft][et][2] + b1v[ft][2], 0.f);
                float h3 = fmaxf(acc[ft][et][3] + b1v[ft][3], 0.f);
                hE[e * 68 + fb + 0] = (unsigned int)f2bf(h0) | ((unsigned int)f2bf(h1) << 16);
                hE[e * 68 + fb + 1] = (unsigned int)f2bf(h2) | ((unsigned int)f2bf(h3) << 16);
            }
        }
    }

    f32x4 acc2[4][4];
    #pragma unroll
    for (int ft = 0; ft < 4; ++ft)
        #pragma unroll
        for (int et = 0; et < 4; ++et)
            acc2[ft][et] = f32x4{0.f, 0.f, 0.f, 0.f};

    // ---- layer 2: K = 128, 4 k-steps ----
    for (int ks = 0; ks < 4; ++ks) {
        {
            const u16x8* gsrc = reinterpret_cast<const u16x8*>(w2Ts + (size_t)(t * 4 + ks) * 4096);
            u16x8* ldst = reinterpret_cast<u16x8*>(sW);
            ldst[tid] = gsrc[tid];
            ldst[tid + 256] = gsrc[tid + 256];
        }
        __syncthreads();
        bf16x8 af[4], bfr[4];
        #pragma unroll
        for (int ft = 0; ft < 4; ++ft)
            af[ft] = *reinterpret_cast<const bf16x8*>(&sW[(64 * wf + 16 * ft + c) * 32 + 8 * g]);
        #pragma unroll
        for (int et = 0; et < 4; ++et)
            bfr[et] = *reinterpret_cast<const bf16x8*>(&sEF[(64 * we + 16 * et + c) * 136 + ks * 32 + 8 * g]);
        #pragma unroll
        for (int ft = 0; ft < 4; ++ft)
            #pragma unroll
            for (int et = 0; et < 4; ++et)
                acc2[ft][et] = __builtin_amdgcn_mfma_f32_16x16x32_bf16(af[ft], bfr[et], acc2[ft][et], 0, 0, 0);
        __syncthreads();
    }

    float b2v[4][4];
    #pragma unroll
    for (int ft = 0; ft < 4; ++ft)
        #pragma unroll
        for (int r = 0; r < 4; ++r)
            b2v[ft][r] = b2[t * D_OUT + 64 * wf + 16 * ft + 4 * g + r];

    #pragma unroll
    for (int et = 0; et < 4; ++et) {
        int e = 64 * we + 16 * et + c;
        if (e < nval) {
            if (USE_MSG) {
                // stream bf16 message row at type-sorted position (coalesced by L2 write-combine)
                unsigned int* orow = reinterpret_cast<unsigned int*>(msg) + ((size_t)(base + e) << 6);
                #pragma unroll
                for (int ft = 0; ft < 4; ++ft) {
                    int cb = 32 * wf + 8 * ft + 2 * g;
                    float m0 = acc2[ft][et][0] + b2v[ft][0];
                    float m1 = acc2[ft][et][1] + b2v[ft][1];
                    float m2 = acc2[ft][et][2] + b2v[ft][2];
                    float m3 = acc2[ft][et][3] + b2v[ft][3];
                    uint2 pk;
                    pk.x = (unsigned int)f2bf(m0) | ((unsigned int)f2bf(m1) << 16);
                    pk.y = (unsigned int)f2bf(m2) | ((unsigned int)f2bf(m3) << 16);
                    *reinterpret_cast<uint2*>(orow + cb) = pk;
                }
            } else {
                float* orow = out + (size_t)sColS[e] * D_OUT;
                #pragma unroll
                for (int ft = 0; ft < 4; ++ft) {
                    int fb = 64 * wf + 16 * ft + 4 * g;
                    #pragma unroll
                    for (int r = 0; r < 4; ++r)
                        atomicAdd(&orow[fb + r], acc2[ft][et][r] + b2v[ft][r]);
                }
            }
        }
    }
}

// ---------------- per-node segment sum (one wave per node, exclusive write) ----------------
__global__ __launch_bounds__(256) void k_agg(const unsigned short* __restrict__ msg,
                                             const int* __restrict__ list2,
                                             const int* __restrict__ rowptr,
                                             float* __restrict__ out)
{
    const int gw = (blockIdx.x * 256 + threadIdx.x) >> 6;   // global wave id = node
    const int lane = threadIdx.x & 63;
    if (gw >= N_NODES) return;
    const int s = rowptr[gw];
    const int e = rowptr[gw + 1];
    const unsigned int* m32 = reinterpret_cast<const unsigned int*>(msg);
    float a0 = 0.f, a1 = 0.f;
    int j = s;
    for (; j + 4 <= e; j += 4) {
        int i0 = list2[j], i1 = list2[j + 1], i2 = list2[j + 2], i3 = list2[j + 3];
        unsigned int v0 = m32[((size_t)i0 << 6) + lane];
        unsigned int v1 = m32[((size_t)i1 << 6) + lane];
        unsigned int v2 = m32[((size_t)i2 << 6) + lane];
        unsigned int v3 = m32[((size_t)i3 << 6) + lane];
        a0 += __builtin_bit_cast(float, v0 << 16) + __builtin_bit_cast(float, v1 << 16)
            + __builtin_bit_cast(float, v2 << 16) + __builtin_bit_cast(float, v3 << 16);
        a1 += __builtin_bit_cast(float, v0 & 0xFFFF0000u) + __builtin_bit_cast(float, v1 & 0xFFFF0000u)
            + __builtin_bit_cast(float, v2 & 0xFFFF0000u) + __builtin_bit_cast(float, v3 & 0xFFFF0000u);
    }
    for (; j < e; ++j) {
        unsigned int v = m32[((size_t)list2[j] << 6) + lane];
        a0 += __builtin_bit_cast(float, v << 16);
        a1 += __builtin_bit_cast(float, v & 0xFFFF0000u);
    }
    float2 o; o.x = a0; o.y = a1;
    *reinterpret_cast<float2*>(out + (size_t)gw * D_OUT + lane * 2) = o;
}

// ---------------- self-loop GEMM + accum + ReLU + LayerNorm (fp32) ----------------
__global__ __launch_bounds__(256, 2) void k_self_ln(
    const float* __restrict__ x,
    const float* __restrict__ sw,
    const float* __restrict__ sb,
    const float* __restrict__ gamma,
    const float* __restrict__ beta,
    float* __restrict__ out)
{
    const int nb = blockIdx.x * 64;
    const int nClamp = min(64, N_NODES - nb);
    __shared__ __align__(16) float smA[64 * 129];
    __shared__ __align__(16) float smW[KC * 128];
    __shared__ float sRed[256], sRed2[256];
    __shared__ float sMu[64], sRstd[64];
    const int tid = threadIdx.x;

    for (int r = 0; r < 8; ++r) {
        int f4 = tid + 256 * r;
        int node = f4 >> 5;
        int k = (f4 & 31) * 4;
        if (node < nClamp) {
            const float4 v = *reinterpret_cast<const float4*>(x + (size_t)(nb + node) * D_IN + k);
            float* dst = &smA[node * 129 + k];
            dst[0] = v.x; dst[1] = v.y; dst[2] = v.z; dst[3] = v.w;
        }
    }

    const int eg = tid & 15, fg = tid >> 4, f0 = fg * 8;
    float acc[4][8];
    #pragma unroll
    for (int i = 0; i < 8; ++i) {
        float bv = sb[f0 + i];
        #pragma unroll
        for (int j = 0; j < 4; ++j) acc[j][i] = bv;
    }

    for (int kc = 0; kc < D_IN / KC; ++kc) {
        __syncthreads();
        {
            const float4* gsrc = reinterpret_cast<const float4*>(sw + kc * KC * 128);
            float4* ldst = reinterpret_cast<float4*>(smW);
            ldst[tid] = gsrc[tid];
            ldst[tid + 256] = gsrc[tid + 256];
        }
        __syncthreads();
        #pragma unroll
        for (int kk = 0; kk < KC; ++kk) {
            float a[4];
            #pragma unroll
            for (int j = 0; j < 4; ++j) a[j] = smA[(eg * 4 + j) * 129 + kc * KC + kk];
            const float4 w0 = *reinterpret_cast<const float4*>(&smW[kk * 128 + f0]);
            const float4 w1v = *reinterpret_cast<const float4*>(&smW[kk * 128 + f0 + 4]);
            float wv[8] = {w0.x, w0.y, w0.z, w0.w, w1v.x, w1v.y, w1v.z, w1v.w};
            #pragma unroll
            for (int j = 0; j < 4; ++j)
                #pragma unroll
                for (int i = 0; i < 8; ++i)
                    acc[j][i] = fmaf(a[j], wv[i], acc[j][i]);
        }
    }
    __syncthreads();

    #pragma unroll
    for (int j = 0; j < 4; ++j) {
        int node = eg * 4 + j;
        if (node < nClamp) {
            const float* arow = out + (size_t)(nb + node) * D_OUT + f0;
            #pragma unroll
            for (int i = 0; i < 8; ++i) {
                float v = acc[j][i] + arow[i];
                smA[node * 129 + f0 + i] = fmaxf(v, 0.f);
            }
        }
    }
    __syncthreads();

    {
        int node = tid >> 2, q = tid & 3;
        float s = 0.f, ss = 0.f;
        #pragma unroll
        for (int i = 0; i < 32; ++i) {
            float v = smA[node * 129 + q * 32 + i];
            s += v; ss += v * v;
        }
        sRed[tid] = s; sRed2[tid] = ss;
    }
    __syncthreads();
    if (tid < 64) {
        float s = sRed[tid * 4] + sRed[tid * 4 + 1] + sRed[tid * 4 + 2] + sRed[tid * 4 + 3];
        float ss = sRed2[tid * 4] + sRed2[tid * 4 + 1] + sRed2[tid * 4 + 2] + sRed2[tid * 4 + 3];
        float mu = s * (1.f / 128.f);
        float var = ss * (1.f / 128.f) - mu * mu;
        sMu[tid] = mu;
        sRstd[tid] = rsqrtf(var + LN_EPS);
    }
    __syncthreads();

    for (int r = 0; r < 8; ++r) {
        int f4 = tid + 256 * r;
        int node = f4 >> 5;
        int k = (f4 & 31) * 4;
        if (node < nClamp) {
            float mu = sMu[node], rs = sRstd[node];
            const float4 gm = *reinterpret_cast<const float4*>(gamma + k);
            const float4 bt = *reinterpret_cast<const float4*>(beta + k);
            float4 o;
            o.x = (smA[node * 129 + k + 0] - mu) * rs * gm.x + bt.x;
            o.y = (smA[node * 129 + k + 1] - mu) * rs * gm.y + bt.y;
            o.z = (smA[node * 129 + k + 2] - mu) * rs * gm.z + bt.z;
            o.w = (smA[node * 129 + k + 3] - mu) * rs * gm.w + bt.w;
            *reinterpret_cast<float4*>(out + (size_t)(nb + node) * D_OUT + k) = o;
        }
    }
}

extern "C" void kernel_launch(void* const* d_in, const int* in_sizes, int n_in,
                              void* d_out, int out_size, void* d_ws, size_t ws_size,
                              hipStream_t stream) {
    const float* x     = (const float*)d_in[0];
    const int*   ei    = (const int*)d_in[1];
    const int*   attr  = (const int*)d_in[2];
    const float* w1    = (const float*)d_in[3];
    const float* b1    = (const float*)d_in[4];
    const float* w2    = (const float*)d_in[5];
    const float* b2    = (const float*)d_in[6];
    const float* sw    = (const float*)d_in[7];
    const float* sb    = (const float*)d_in[8];
    const float* gamma = (const float*)d_in[9];
    const float* beta  = (const float*)d_in[10];
    float* out = (float*)d_out;

    char* ws = (char*)d_ws;
    int* meta   = (int*)(ws + OFF_META);
    int* sorted = (int*)(ws + OFF_SORTED);
    unsigned short* xb   = (unsigned short*)(ws + OFF_XB);
    unsigned short* w1Ts = (unsigned short*)(ws + OFF_W1T);
    unsigned short* w2Ts = (unsigned short*)(ws + OFF_W2T);

    const bool useMsg = ws_size >= WS_TOTAL_MSG;

    hipMemsetAsync(meta, 0, 64, stream);
    k_cvt_x<<<(N_NODES * D_IN / 4 + 255) / 256, 256, 0, stream>>>(x, xb);
    k_prep_w1<<<(N_TYPES * 8 * 128 * 32 + 255) / 256, 256, 0, stream>>>(w1, w1Ts);
    k_prep_w2<<<(N_TYPES * 4 * 128 * 32 + 255) / 256, 256, 0, stream>>>(w2, w2Ts);
    k_hist<<<(N_EDGES + 255) / 256, 256, 0, stream>>>(attr, meta);
    k_scan<<<1, 1, 0, stream>>>(meta);
    k_scatter<<<(N_EDGES + 255) / 256, 256, 0, stream>>>(attr, meta, sorted);

    if (useMsg) {
        int* colcnt = (int*)(ws + OFF_COLCNT);
        int* rowptr = (int*)(ws + OFF_ROWPTR);
        int* cursor = (int*)(ws + OFF_CURSOR);
        int* list2  = (int*)(ws + OFF_LIST2);
        unsigned short* msg = (unsigned short*)(ws + OFF_MSG);

        hipMemsetAsync(colcnt, 0, (size_t)N_NODES * 4, stream);
        k_hist_col<<<(N_EDGES + 255) / 256, 256, 0, stream>>>(ei, colcnt);
        k_scan_col<<<1, SCAN_T, 0, stream>>>(colcnt, rowptr, cursor);
        k_scatter_col<<<(N_EDGES + 255) / 256, 256, 0, stream>>>(ei, sorted, cursor, list2);

        k_edge<true><<<dim3((N_EDGES + TE - 1) / TE, N_TYPES), 256, 0, stream>>>(
            xb, ei, meta, sorted, w1Ts, b1, w2Ts, b2, out, msg);
        k_agg<<<(N_NODES * 64 + 255) / 256, 256, 0, stream>>>(msg, list2, rowptr, out);
    } else {
        hipMemsetAsync(out, 0, (size_t)N_NODES * D_OUT * sizeof(float), stream);
        k_edge<false><<<dim3((N_EDGES + TE - 1) / TE, N_TYPES), 256, 0, stream>>>(
            xb, ei, meta, sorted, w1Ts, b1, w2Ts, b2, out, nullptr);
    }

    k_self_ln<<<(N_NODES + 63) / 64, 256, 0, stream>>>(x, sw, sb, gamma, beta, out);
}